// Round 10
// baseline (608.872 us; speedup 1.0000x reference)
//
#include <hip/hip_runtime.h>
#include <hip/hip_bf16.h>

typedef _Float16 f16;
typedef _Float16 f16x4 __attribute__((ext_vector_type(4)));
typedef _Float16 f16x8 __attribute__((ext_vector_type(8)));
typedef float f32x4 __attribute__((ext_vector_type(4)));

#define D 128
#define N_CLS 40
#define BN 128       // nodes per bucket
#define NBMAX 1024   // padded bucket count
#define G_PRE 2048   // preprocessing grid (chunks over edges)

// Gather operand (GEMM output) is feature-sliced: 4 slices x 32 feats = 64B/row,
// slice-major: HS_blk[s][i][f], f in [0,32). Every L1 miss delivers a fully-
// used 64B line; 4 x e = 12.8M lines/dispatch is the compulsory floor for f16
// (H-MSHR model confirmed round 8: 140->123us, FETCH 91->407MB as predicted).
// Aggregation OUTPUT is row-major (consumed densely by GEMM2 / classifier).
// Preprocessing v3: atomic-free two-pass binning. k_hist2 stores per-(block,
// bucket) counts to bh; k_lofs turns bh columns into exclusive offsets and
// emits bucket totals; k_place3 reads dst/src ONCE and scatters using
// precomputed offsets (random writes confined to 16KB L1-resident windows —
// round 4 showed one-pass global scatter costs 194MB write-allocate, 321us).

// ---- 1. per-chunk bucket histogram: bh[b][j] = #edges of chunk b in bucket j
__global__ __launch_bounds__(256) void k_hist2(const int* __restrict__ dst,
                                               int* __restrict__ bh, int e) {
  __shared__ int lh[NBMAX];
  int b = blockIdx.x, t = threadIdx.x;
  for (int j = t; j < NBMAX; j += 256) lh[j] = 0;
  __syncthreads();
  int chunk = (e + G_PRE - 1) / G_PRE;
  int lo = b * chunk, hi = min(e, lo + chunk);
  for (int q = lo + t; q < hi; q += 256) atomicAdd(&lh[dst[q] >> 7], 1);
  __syncthreads();
  for (int j = t; j < NBMAX; j += 256) bh[(size_t)b * NBMAX + j] = lh[j];
}

// ---- 2. per-bucket scan over chunks: bh[b][j] -> exclusive offset within
//      bucket j; bcnt[j] = bucket total. One block per bucket, no atomics.
__global__ __launch_bounds__(256) void k_lofs(int* __restrict__ bh,
                                              int* __restrict__ bcnt) {
  int j = blockIdx.x, t = threadIdx.x;
  __shared__ int s[256];
  int v[8];
#pragma unroll
  for (int k = 0; k < 8; ++k) v[k] = bh[(size_t)(t * 8 + k) * NBMAX + j];
  int tt = 0;
#pragma unroll
  for (int k = 0; k < 8; ++k) { int x = v[k]; v[k] = tt; tt += x; }
  s[t] = tt;
  __syncthreads();
  for (int off = 1; off < 256; off <<= 1) {
    int a = (t >= off) ? s[t - off] : 0;
    __syncthreads();
    s[t] += a;
    __syncthreads();
  }
  int ex = s[t] - tt;  // exclusive over threads
  if (t == 255) bcnt[j] = s[255];
#pragma unroll
  for (int k = 0; k < 8; ++k) bh[(size_t)(t * 8 + k) * NBMAX + j] = ex + v[k];
}

// ---- 3. exclusive scan of bucket totals -> bbase ----
__global__ __launch_bounds__(1024) void k_bscan(const int* __restrict__ bcnt,
                                                int* __restrict__ bbase) {
  __shared__ int sums[NBMAX];
  int t = threadIdx.x;
  int c = bcnt[t];
  sums[t] = c;
  __syncthreads();
  for (int off = 1; off < NBMAX; off <<= 1) {
    int a = (t >= off) ? sums[t - off] : 0;
    __syncthreads();
    sums[t] += a;
    __syncthreads();
  }
  bbase[t] = sums[t] - c;
}

// ---- 4. placement: single pass over dst/src, scatter into bucket-major binned
__global__ __launch_bounds__(256) void k_place3(const int* __restrict__ src,
                                                const int* __restrict__ dst,
                                                const int* __restrict__ bh,
                                                const int* __restrict__ bbase,
                                                unsigned int* __restrict__ binned,
                                                int e) {
  __shared__ int lofs[NBMAX];
  __shared__ int lcur[NBMAX];
  int b = blockIdx.x, t = threadIdx.x;
  for (int j = t; j < NBMAX; j += 256) {
    lofs[j] = bh[(size_t)b * NBMAX + j] + bbase[j];
    lcur[j] = 0;
  }
  __syncthreads();
  int chunk = (e + G_PRE - 1) / G_PRE;
  int lo = b * chunk, hi = min(e, lo + chunk);
  for (int q = lo + t; q < hi; q += 256) {
    int d = dst[q];
    int bb = d >> 7;
    int r = atomicAdd(&lcur[bb], 1);
    binned[lofs[bb] + r] = ((unsigned int)(d & 127) << 17) | (unsigned int)src[q];
  }
}

// ---- 5. per-bucket counting sort -> CSR + deg + isd + row_start ----
__global__ __launch_bounds__(256) void k_csr(const unsigned int* __restrict__ binned,
                                             const int* __restrict__ bbase,
                                             const int* __restrict__ bcnt,
                                             int* __restrict__ csr,
                                             int* __restrict__ deg,
                                             float* __restrict__ isd,
                                             int* __restrict__ row_start, int n) {
  int b = blockIdx.x;
  int lo = bbase[b], hi = lo + bcnt[b];
  __shared__ int h[BN];
  __shared__ int sc[BN];
  __shared__ int cur[BN];
  int t = threadIdx.x;
  if (t < BN) h[t] = 0;
  __syncthreads();
  for (int q = lo + t; q < hi; q += 256) atomicAdd(&h[binned[q] >> 17], 1);
  __syncthreads();
  if (t < BN) sc[t] = h[t];
  __syncthreads();
  for (int off = 1; off < BN; off <<= 1) {
    int a = 0;
    if (t < BN && t >= off) a = sc[t - off];
    __syncthreads();
    if (t < BN) sc[t] += a;
    __syncthreads();
  }
  if (t < BN) {
    int excl = sc[t] - h[t];
    cur[t] = lo + excl;
    int i = b * BN + t;
    if (i < n) {
      deg[i] = h[t];
      isd[i] = rsqrtf((float)(h[t] + 1));
      row_start[i] = lo + excl;
    }
  }
  __syncthreads();
  for (int q = lo + t; q < hi; q += 256) {
    unsigned int u = binned[q];
    int p = atomicAdd(&cur[u >> 17], 1);
    csr[p] = (int)(u & 0x1FFFF);
  }
}

// ---- one-time weight transpose: Wt[c][k] = (f16)W[k*128+c], both layers ----
__global__ __launch_bounds__(256) void k_wt(const float* __restrict__ W1,
                                            const float* __restrict__ W2,
                                            f16* __restrict__ O1,
                                            f16* __restrict__ O2) {
  const float* W = blockIdx.x ? W2 : W1;
  f16* O = blockIdx.x ? O2 : O1;
  __shared__ f16 lt[D][136];
  int t = threadIdx.x;
  for (int q = t; q < D * D; q += 256) {
    int k = q >> 7, c = q & 127;
    lt[c][k] = (f16)W[q];
  }
  __syncthreads();
  for (int q = t; q < D * 16; q += 256) {
    int row = q >> 4, cb = (q & 15) << 3;
    *(f16x8*)(O + ((size_t)row << 7) + cb) = *(const f16x8*)&lt[row][cb];
  }
}

// ---- MFMA GEMM v2: HS_blk = isd[i] * (X @ W), fp32 accum ----
// Block: 256 thr = 4 waves, 64 rows x 128 cols, K=128 in 4 steps of 32.
// A fragment loaded DIRECT from global (no LDS: waves own disjoint rows).
// B from precomputed Wt (f16 [col][k]) staged via coalesced f16x8 loads.
// C/D (guide-verified m89): col = lane&15, row = (lane>>4)*4 + reg.
// Epilogue: acc -> LDS ot tile -> 4 x fully-coalesced f16x8 stores/thread.
template <bool HALF_IN>
__global__ __launch_bounds__(256) void k_gemm_m(const void* __restrict__ Xv,
                                                const f16* __restrict__ Wtr,
                                                const float* __restrict__ isd,
                                                f16* __restrict__ HS, int n) {
  __shared__ f16 Wt[D][136];
  __shared__ f16 ot[64][136];
  const size_t ss = (size_t)n * 32;  // slice stride in f16 elems (4x32 layout)
  int t = threadIdx.x;
  int r0 = blockIdx.x * 64;
  for (int q = t; q < D * 16; q += 256) {
    int row = q >> 4, cb = (q & 15) << 3;
    *(f16x8*)&Wt[row][cb] = *(const f16x8*)(Wtr + ((size_t)row << 7) + cb);
  }
  __syncthreads();

  int wave = t >> 6, lane = t & 63;
  int lw = lane & 15, kg = lane >> 4;
  int arow = r0 + (wave << 4) + lw;
  if (arow >= n) arow = n - 1;  // clamp: tail-block lanes read a valid row
  f32x4 acc[8];
#pragma unroll
  for (int ct = 0; ct < 8; ++ct) acc[ct] = (f32x4)0.f;
#pragma unroll
  for (int ks = 0; ks < 4; ++ks) {
    f16x8 af;
    if (HALF_IN) {
      af = *(const f16x8*)((const f16*)Xv + (size_t)arow * D + ks * 32 + kg * 8);
    } else {
      const float* xp = (const float*)Xv + (size_t)arow * D + ks * 32 + kg * 8;
      float4 x0 = *(const float4*)xp;
      float4 x1 = *(const float4*)(xp + 4);
      af[0] = (f16)x0.x; af[1] = (f16)x0.y; af[2] = (f16)x0.z; af[3] = (f16)x0.w;
      af[4] = (f16)x1.x; af[5] = (f16)x1.y; af[6] = (f16)x1.z; af[7] = (f16)x1.w;
    }
#pragma unroll
    for (int ct = 0; ct < 8; ++ct) {
      f16x8 bf = *(const f16x8*)&Wt[ct * 16 + lw][ks * 32 + kg * 8];
      acc[ct] = __builtin_amdgcn_mfma_f32_16x16x32_f16(af, bf, acc[ct], 0, 0, 0);
    }
  }
  int lrow = (wave << 4) + (kg << 2);
  float sv[4];
#pragma unroll
  for (int rr = 0; rr < 4; ++rr) {
    int node = r0 + lrow + rr;
    sv[rr] = isd[node < n ? node : n - 1];
  }
#pragma unroll
  for (int ct = 0; ct < 8; ++ct)
#pragma unroll
    for (int rr = 0; rr < 4; ++rr)
      ot[lrow + rr][ct * 16 + lw] = (f16)(acc[ct][rr] * sv[rr]);
  __syncthreads();
  {
    int orow = t >> 2, cb = (t & 3) << 3;
    if (r0 + orow < n) {
#pragma unroll
      for (int s = 0; s < 4; ++s)
        *(f16x8*)(HS + (size_t)s * ss + (size_t)(r0 + orow) * 32 + cb) =
            *(const f16x8*)&ot[orow][s * 32 + cb];
    }
  }
}

__device__ inline f16x8 shfl_xor_f16x8(f16x8 v, int m) {
  union { f16x8 h; int i[4]; } u;
  u.h = v;
#pragma unroll
  for (int k = 0; k < 4; ++k) u.i[k] = __shfl_xor(u.i[k], m);
  return u.h;
}

// ---- sliced aggregation (4 slices x 32 feats, 64B rows) — UNCHANGED ----
__global__ __launch_bounds__(256) void k_aggs(const f16* __restrict__ HS,
                                              const int* __restrict__ csr,
                                              const int* __restrict__ row_start,
                                              const int* __restrict__ deg,
                                              const float* __restrict__ bias,
                                              f16* __restrict__ G, int n) {
  const size_t ss = (size_t)n * 32;
  int t = threadIdx.x;
  int wave = t >> 6, lane = t & 63;
  int g = lane >> 4, r = lane & 15;
  int s = blockIdx.x & 3;
  int i0 = ((blockIdx.x >> 2) << 4) + (wave << 2) + g;
  bool ok = i0 < n;
  int i = ok ? i0 : n - 1;
  int q = r & 3, er = r >> 2;
  int dg = deg[i];
  const int* cp = csr + row_start[i];           // safe reads: +64 pad
  const char* sbase = (const char*)(HS + (size_t)s * ss);  // wave-uniform
  unsigned qofs = (unsigned)(q << 4);
  f16x8 a0 = (f16x8)0, a1 = (f16x8)0, a2 = (f16x8)0, a3 = (f16x8)0;
  int iA = cp[er];
  int iB = cp[er + 4];
  int iC = cp[er + 8];
  int iD = cp[er + 12];
  for (int u = 0; u < dg; u += 16) {
    unsigned oA = ((unsigned)iA << 6) + qofs;
    unsigned oB = ((unsigned)iB << 6) + qofs;
    unsigned oC = ((unsigned)iC << 6) + qofs;
    unsigned oD = ((unsigned)iD << 6) + qofs;
    iA = cp[u + 16 + er];
    iB = cp[u + 20 + er];
    iC = cp[u + 24 + er];
    iD = cp[u + 28 + er];
    if (u + er < dg)
      a0 += *(const f16x8*)(sbase + oA);
    if (u + 4 + er < dg)
      a1 += *(const f16x8*)(sbase + oB);
    if (u + 8 + er < dg)
      a2 += *(const f16x8*)(sbase + oC);
    if (u + 12 + er < dg)
      a3 += *(const f16x8*)(sbase + oD);
  }
  f16x8 tv = (a0 + a1) + (a2 + a3);
  tv += shfl_xor_f16x8(tv, 4);
  tv += shfl_xor_f16x8(tv, 8);
  f16x8 svv = *(const f16x8*)(sbase + ((unsigned)i << 6) + qofs);
  float di = rsqrtf((float)(dg + 1));
  const float* bp = bias + s * 32 + (q << 3);
  float4 b0 = *(const float4*)bp;
  float4 b1 = *(const float4*)(bp + 4);
  float bv[8] = {b0.x, b0.y, b0.z, b0.w, b1.x, b1.y, b1.z, b1.w};
  f16x8 ov;
#pragma unroll
  for (int j = 0; j < 8; ++j) {
    float v = di * ((float)tv[j] + (float)svv[j]) + bv[j];
    v = v > 0.f ? v : 0.f;
    ov[j] = (f16)v;
  }
  if (ok && er == 0)
    *(f16x8*)(G + (size_t)i * D + s * 32 + (q << 3)) = ov;
}

// ---- classifier v3: out = H @ Wl + bl, Wl^T staged in LDS, 128 nodes/block ----
__global__ __launch_bounds__(256) void k_cls(const f16* __restrict__ H,
                                             const float* __restrict__ Wl,
                                             const float* __restrict__ bl,
                                             float* __restrict__ out, int n) {
  __shared__ float wt[N_CLS][D];
  int t = threadIdx.x;
  for (int q = t; q < D * N_CLS; q += 256) {
    int k = q / N_CLS, c = q - k * N_CLS;
    wt[c][k] = Wl[q];
  }
  int wv = t >> 6, lane = t & 63, g = lane >> 4, l = lane & 15;
  float bb0 = bl[l];
  float bb1 = bl[16 + l];
  float bb2 = (l < 8) ? bl[32 + l] : 0.f;
  __syncthreads();
  int node0 = (blockIdx.x << 7) + (wv << 2) + g;
  for (int it = 0; it < 8; ++it) {
    int node = node0 + it * 16;
    if (node >= n) break;
    f16x8 h = *(const f16x8*)(H + (size_t)node * D + l * 8);
    float hf[8];
#pragma unroll
    for (int j = 0; j < 8; ++j) hf[j] = (float)h[j];
    float r0 = bb0, r1 = bb1, r2 = bb2;
#pragma unroll 4
    for (int c = 0; c < N_CLS; ++c) {
      const float* wp = &wt[c][l * 8];
      float4 w0 = *(const float4*)wp;
      float4 w1 = *(const float4*)(wp + 4);
      float p = hf[0] * w0.x + hf[1] * w0.y + hf[2] * w0.z + hf[3] * w0.w +
                hf[4] * w1.x + hf[5] * w1.y + hf[6] * w1.z + hf[7] * w1.w;
      p += __shfl_xor(p, 1);
      p += __shfl_xor(p, 2);
      p += __shfl_xor(p, 4);
      p += __shfl_xor(p, 8);
      if ((c & 15) == l) {
        if (c < 16) r0 += p;
        else if (c < 32) r1 += p;
        else r2 += p;
      }
    }
    float* op = out + (size_t)node * N_CLS;
    op[l] = r0;
    op[16 + l] = r1;
    if (l < 8) op[32 + l] = r2;
  }
}

extern "C" void kernel_launch(void* const* d_in, const int* in_sizes, int n_in,
                              void* d_out, int out_size, void* d_ws, size_t ws_size,
                              hipStream_t stream) {
  const float* x  = (const float*)d_in[0];
  const int*   ei = (const int*)d_in[1];
  const float* W1 = (const float*)d_in[2];
  const float* b1 = (const float*)d_in[3];
  const float* W2 = (const float*)d_in[4];
  const float* b2 = (const float*)d_in[5];
  const float* Wl = (const float*)d_in[6];
  const float* bl = (const float*)d_in[7];
  float* out = (float*)d_out;

  const int n = in_sizes[0] / D;  // 100000
  const int e = in_sizes[1] / 2;  // 3200000
  const int* src = ei;
  const int* dst = ei + e;
  const int nb = (n + BN - 1) / BN;  // 782

  char* ws = (char*)d_ws;
  size_t off = 0;
  auto alloc = [&](size_t bytes) -> void* {
    void* p = ws + off;
    off += (bytes + 255) & ~(size_t)255;
    return p;
  };
  int*   bcnt      = (int*)alloc(NBMAX * 4);
  int*   bbase     = (int*)alloc(NBMAX * 4);
  int*   deg       = (int*)alloc((size_t)n * 4);
  int*   row_start = (int*)alloc((size_t)n * 4);
  float* isd       = (float*)alloc((size_t)n * 4);
  int*   csr       = (int*)alloc(((size_t)e + 64) * 4);  // +64 pad: clamp-free
  f16*   Wt1       = (f16*)alloc((size_t)D * D * 2);
  f16*   Wt2       = (f16*)alloc((size_t)D * D * 2);
  f16*   hA        = (f16*)alloc((size_t)n * D * 2);
  f16*   hB        = (f16*)alloc((size_t)n * D * 2);
  unsigned int* binned = (unsigned int*)hA;  // dead before gemm1 writes hA
  int*   bh        = (int*)hB;               // 8MB; dead before agg1 writes hB

  hipMemsetAsync(csr + e, 0, 64 * 4, stream);  // pad -> valid index 0

  k_hist2<<<G_PRE, 256, 0, stream>>>(dst, bh, e);
  k_lofs<<<NBMAX, 256, 0, stream>>>(bh, bcnt);
  k_bscan<<<1, 1024, 0, stream>>>(bcnt, bbase);
  k_place3<<<G_PRE, 256, 0, stream>>>(src, dst, bh, bbase, binned, e);
  k_csr<<<nb, 256, 0, stream>>>(binned, bbase, bcnt, csr, deg, isd, row_start, n);
  k_wt<<<2, 256, 0, stream>>>(W1, W2, Wt1, Wt2);

  int gblocks = (n + 63) / 64;
  int ablocks = ((n + 15) / 16) * 4;  // node-groups x 4 slices
  // layer 1: MFMA gemm -> slice-major hA; agg -> row-major hB
  k_gemm_m<false><<<gblocks, 256, 0, stream>>>(x, Wt1, isd, hA, n);
  k_aggs<<<ablocks, 256, 0, stream>>>(hA, csr, row_start, deg, b1, hB, n);
  // layer 2: MFMA gemm (row-major f16 in) -> slice-major hA; agg -> row-major hB
  k_gemm_m<true><<<gblocks, 256, 0, stream>>>(hB, Wt2, isd, hA, n);
  k_aggs<<<ablocks, 256, 0, stream>>>(hA, csr, row_start, deg, b2, hB, n);
  // classifier
  k_cls<<<(n + 127) / 128, 256, 0, stream>>>(hB, Wl, bl, out, n);
}